// Round 1
// baseline (177.929 us; speedup 1.0000x reference)
//
#include <hip/hip_runtime.h>
#include <math.h>

// Problem constants
#define BD  128           // batch per side
#define N2  256           // 2*BD (concat size)
#define DIM 768
#define EPSF 1e-8f
#define INV_TEMP 20.0f    // 1/0.05

// Workspace layout (float offsets)
#define OFF_GS   0                     // [256*256] Gram of s
#define OFF_GT   65536                 // [256*256] Gram of t
#define OFF_SC   131072                // [128*128] contrastive scores (pre-scaled)
#define OFF_INVS 147456                // [256*256] 1/(sqrt(ds_s)+eps)
#define OFF_INVT 212992                // [256*256] 1/(sqrt(ds_t)+eps)
#define OFF_ACC  278528                // [8] accumulators: 0 sum_ds, 1 sum_dt, 2 dist_sum, 3 angle_sum, 4 contr_sum

__device__ inline float wave_reduce_sum(float v) {
    #pragma unroll
    for (int o = 32; o > 0; o >>= 1) v += __shfl_down(v, o, 64);
    return v;
}

// ---------------------------------------------------------------------------
// GEMM: z=0 -> Gs = s @ s^T (s = concat(sq,sp))
//       z=1 -> Gt = t @ t^T
//       z=2 -> scores = (sq @ sp^T) * 20
// ---------------------------------------------------------------------------
__global__ __launch_bounds__(256) void gemm_kernel(
        const float* __restrict__ sq, const float* __restrict__ sp,
        const float* __restrict__ tq, const float* __restrict__ tp,
        float* __restrict__ ws) {
    const int z  = blockIdx.z;
    const int bx = blockIdx.x, by = blockIdx.y;
    const int tx = threadIdx.x, ty = threadIdx.y;
    if (z == 2 && (bx >= 8 || by >= 8)) return;  // scores is 128x128

    __shared__ float As[16][17];
    __shared__ float Bs[16][17];

    const int row = by * 16 + ty;
    const int col = bx * 16 + tx;
    float acc = 0.f;

    for (int k0 = 0; k0 < DIM; k0 += 16) {
        const int ar = by * 16 + ty;      // A-row this thread stages
        const int br = bx * 16 + ty;      // B-row this thread stages
        const int kk = k0 + tx;
        float av, bv;
        if (z == 0) {
            av = (ar < BD) ? sq[ar * DIM + kk] : sp[(ar - BD) * DIM + kk];
            bv = (br < BD) ? sq[br * DIM + kk] : sp[(br - BD) * DIM + kk];
        } else if (z == 1) {
            av = (ar < BD) ? tq[ar * DIM + kk] : tp[(ar - BD) * DIM + kk];
            bv = (br < BD) ? tq[br * DIM + kk] : tp[(br - BD) * DIM + kk];
        } else {
            av = sq[ar * DIM + kk];
            bv = sp[br * DIM + kk];
        }
        As[ty][tx] = av;
        Bs[ty][tx] = bv;
        __syncthreads();
        #pragma unroll
        for (int k2 = 0; k2 < 16; ++k2) acc += As[ty][k2] * Bs[tx][k2];
        __syncthreads();
    }

    if (z == 0)      ws[OFF_GS + row * N2 + col] = acc;
    else if (z == 1) ws[OFF_GT + row * N2 + col] = acc;
    else             ws[OFF_SC + row * BD + col] = acc * INV_TEMP;
}

// ---------------------------------------------------------------------------
// prep: inv_s/inv_t = 1/(sqrt(ds)+eps), plus masked sums of ds, dt (j>i)
// grid 256 blocks x 256 threads; block=i, thread=j
// ---------------------------------------------------------------------------
__global__ __launch_bounds__(256) void prep_kernel(float* __restrict__ ws) {
    const float* Gs = ws + OFF_GS;
    const float* Gt = ws + OFF_GT;
    float* inv_s = ws + OFF_INVS;
    float* inv_t = ws + OFF_INVT;
    float* acc   = ws + OFF_ACC;

    const int i = blockIdx.x, j = threadIdx.x;
    const float Gii = Gs[i * 257], Gjj = Gs[j * 257], Gij = Gs[i * N2 + j];
    const float ds  = fmaxf(Gii + Gjj - 2.f * Gij, 0.f);
    inv_s[i * N2 + j] = 1.f / (sqrtf(ds) + EPSF);

    const float Tii = Gt[i * 257], Tjj = Gt[j * 257], Tij = Gt[i * N2 + j];
    const float dt  = fmaxf(Tii + Tjj - 2.f * Tij, 0.f);
    inv_t[i * N2 + j] = 1.f / (sqrtf(dt) + EPSF);

    float vs = (j > i) ? ds : 0.f;
    float vt = (j > i) ? dt : 0.f;
    vs = wave_reduce_sum(vs);
    vt = wave_reduce_sum(vt);
    if ((j & 63) == 0) {
        atomicAdd(&acc[0], vs);
        atomicAdd(&acc[1], vt);
    }
}

// ---------------------------------------------------------------------------
// contrastive: per-row logsumexp - diag; grid 128 blocks x 128 threads
// ---------------------------------------------------------------------------
__global__ __launch_bounds__(128) void contrastive_kernel(float* __restrict__ ws) {
    __shared__ float red[2];
    const float* sc = ws + OFF_SC;
    float* acc = ws + OFF_ACC;
    const int i = blockIdx.x, j = threadIdx.x;
    const float s = sc[i * BD + j];

    float m = s;
    #pragma unroll
    for (int o = 32; o > 0; o >>= 1) m = fmaxf(m, __shfl_down(m, o, 64));
    if ((j & 63) == 0) red[j >> 6] = m;
    __syncthreads();
    const float rowmax = fmaxf(red[0], red[1]);
    __syncthreads();

    float e = expf(s - rowmax);
    e = wave_reduce_sum(e);
    if ((j & 63) == 0) red[j >> 6] = e;
    __syncthreads();
    if (j == 0) {
        const float logZ = rowmax + logf(red[0] + red[1]);
        atomicAdd(&acc[4], logZ - sc[i * BD + i]);
    }
}

// ---------------------------------------------------------------------------
// distance: huber(ds/mean_sd - dt/mean_td) over j>i
// ---------------------------------------------------------------------------
__global__ __launch_bounds__(256) void dist_kernel(float* __restrict__ ws) {
    const float* Gs = ws + OFF_GS;
    const float* Gt = ws + OFF_GT;
    float* acc = ws + OFF_ACC;

    const float mean_sd = acc[0] / 32640.f + EPSF;
    const float mean_td = acc[1] / 32640.f + EPSF;

    const int i = blockIdx.x, j = threadIdx.x;
    float v = 0.f;
    if (j > i) {
        const float ds = fmaxf(Gs[i * 257] + Gs[j * 257] - 2.f * Gs[i * N2 + j], 0.f);
        const float dt = fmaxf(Gt[i * 257] + Gt[j * 257] - 2.f * Gt[i * N2 + j], 0.f);
        const float d  = ds / mean_sd - dt / mean_td;
        const float a  = fabsf(d);
        v = (a < 1.f) ? 0.5f * a * a : a - 0.5f;
    }
    v = wave_reduce_sum(v);
    if ((j & 63) == 0) atomicAdd(&acc[2], v);
}

// ---------------------------------------------------------------------------
// angle: sum over i!=j, i!=k, j!=k of huber(ps - pt)
// ps[i,j,k] = (Gs[j,j]-Gs[j,k]-Gs[i,j]+Gs[i,k]) * inv_s[i,j] * inv_s[j,k]
// grid (16,16) blocks of 16x16 threads; thread owns one (i,j), loops k.
// ---------------------------------------------------------------------------
__global__ __launch_bounds__(256) void angle_kernel(float* __restrict__ ws) {
    const float* Gs = ws + OFF_GS;
    const float* Gt = ws + OFF_GT;
    const float* inv_s = ws + OFF_INVS;
    const float* inv_t = ws + OFF_INVT;
    float* acc = ws + OFF_ACC;

    __shared__ float sGsJ[16][65], sGsI[16][65], sIsJ[16][65];
    __shared__ float sGtJ[16][65], sGtI[16][65], sItJ[16][65];

    const int jj = threadIdx.x, ii = threadIdx.y;
    const int i0 = blockIdx.y * 16, j0 = blockIdx.x * 16;
    const int i = i0 + ii, j = j0 + jj;
    const int t = ii * 16 + jj;

    const float c0s = Gs[j * 257] - Gs[i * N2 + j];
    const float c0t = Gt[j * 257] - Gt[i * N2 + j];
    const float wis = inv_s[i * N2 + j];
    const float wit = inv_t[i * N2 + j];

    float sum = 0.f;
    for (int k0 = 0; k0 < N2; k0 += 64) {
        __syncthreads();
        for (int idx = t; idx < 1024; idx += 256) {
            const int r = idx >> 6, c = idx & 63;
            sGsJ[r][c] = Gs[(j0 + r) * N2 + k0 + c];
            sGsI[r][c] = Gs[(i0 + r) * N2 + k0 + c];
            sIsJ[r][c] = inv_s[(j0 + r) * N2 + k0 + c];
            sGtJ[r][c] = Gt[(j0 + r) * N2 + k0 + c];
            sGtI[r][c] = Gt[(i0 + r) * N2 + k0 + c];
            sItJ[r][c] = inv_t[(j0 + r) * N2 + k0 + c];
        }
        __syncthreads();
        if (i == j) continue;   // after both barriers: uniform per-thread skip is safe
        for (int c = 0; c < 64; ++c) {
            const int k = k0 + c;
            if (k == i || k == j) continue;
            const float ps = (c0s - sGsJ[jj][c] + sGsI[ii][c]) * wis * sIsJ[jj][c];
            const float pt = (c0t - sGtJ[jj][c] + sGtI[ii][c]) * wit * sItJ[jj][c];
            const float a = fabsf(ps - pt);
            sum += (a < 1.f) ? 0.5f * a * a : a - 0.5f;
        }
    }
    sum = wave_reduce_sum(sum);
    if ((t & 63) == 0) atomicAdd(&acc[3], sum);
}

// ---------------------------------------------------------------------------
// finalize: (total, contrastive, kd)
// ---------------------------------------------------------------------------
__global__ void finalize_kernel(const float* __restrict__ acc, float* __restrict__ out) {
    const float contrastive = acc[4] / 128.f;
    const float dist  = acc[2] / 32640.f;
    const float angle = acc[3] / 16581120.f;   // 256*255*254
    const float kd = 0.5f * dist + 0.5f * angle;
    out[0] = contrastive + kd;
    out[1] = contrastive;
    out[2] = kd;
}

extern "C" void kernel_launch(void* const* d_in, const int* in_sizes, int n_in,
                              void* d_out, int out_size, void* d_ws, size_t ws_size,
                              hipStream_t stream) {
    (void)in_sizes; (void)n_in; (void)out_size; (void)ws_size;
    const float* sq = (const float*)d_in[0];
    const float* sp = (const float*)d_in[1];
    const float* tq = (const float*)d_in[2];
    const float* tp = (const float*)d_in[3];
    float* ws  = (float*)d_ws;
    float* out = (float*)d_out;

    // zero the accumulators (ws is poisoned 0xAA before every call)
    hipMemsetAsync(ws + OFF_ACC, 0, 8 * sizeof(float), stream);

    gemm_kernel<<<dim3(16, 16, 3), dim3(16, 16), 0, stream>>>(sq, sp, tq, tp, ws);
    prep_kernel<<<256, 256, 0, stream>>>(ws);
    contrastive_kernel<<<128, 128, 0, stream>>>(ws);
    dist_kernel<<<256, 256, 0, stream>>>(ws);
    angle_kernel<<<dim3(16, 16), dim3(16, 16), 0, stream>>>(ws);
    finalize_kernel<<<1, 1, 0, stream>>>(ws + OFF_ACC, out);
}

// Round 2
// 92.817 us; speedup vs baseline: 1.9170x; 1.9170x over previous
//
#include <hip/hip_runtime.h>
#include <math.h>

#define N2   256
#define DIM  768
#define EPSF 1e-8f

// ws layout (float offsets). Total 262464 floats = 1,049,856 B (< proven 1.11 MB)
#define OFF_GS   0          // [65536] Gram of s (atomic-accumulated, pre-zeroed)
#define OFF_GT   65536      // [65536] Gram of t
#define OFF_BKT  131072     // [320] buckets (pre-zeroed): DS,DT,DIST,ANG,CON x64
#define OFF_INVS 131392     // [65536]
#define OFF_INVT 196928     // [65536]
#define BKT_DS   0
#define BKT_DT   64
#define BKT_DIST 128
#define BKT_ANG  192
#define BKT_CON  256

__device__ inline float wave_reduce_sum(float v) {
    #pragma unroll
    for (int o = 32; o > 0; o >>= 1) v += __shfl_down(v, o, 64);
    return v;
}
__device__ inline float wave_reduce_max(float v) {
    #pragma unroll
    for (int o = 32; o > 0; o >>= 1) v = fmaxf(v, __shfl_down(v, o, 64));
    return v;
}

// ---------------------------------------------------------------------------
// GEMM: Gs = s@s^T, Gt = t@t^T. 512 blocks x 64 threads.
// b&3 = K-chunk (192 each), (b>>2)&1 = matrix, b>>3 = 32x32 tile (8x8 grid).
// Thread-tile 4x4, float4 LDS frags, atomicAdd accumulate into zeroed Gram.
// ---------------------------------------------------------------------------
__global__ __launch_bounds__(64) void gemm_kernel(
        const float* __restrict__ sq, const float* __restrict__ sp,
        const float* __restrict__ tq, const float* __restrict__ tp,
        float* __restrict__ ws) {
    const int b = blockIdx.x;
    const int chunk = b & 3;
    const int mat = (b >> 2) & 1;
    const int tile = b >> 3;
    const int m0 = (tile >> 3) * 32, n0 = (tile & 7) * 32;
    const int t = threadIdx.x;
    const float* q = mat ? tq : sq;
    const float* p = mat ? tp : sp;
    float* G = ws + (mat ? OFF_GT : OFF_GS);

    __shared__ float As[8][36];   // [k][row], pad 36 keeps float4 rows 16B-aligned
    __shared__ float Bs[8][36];

    const int ty = t >> 3, tx = t & 7;          // 8x8 compute grid
    const int sr = t >> 1, kq = (t & 1) * 4;    // staging: 32 rows x 2 k-quads
    const int arow = m0 + sr, brow = n0 + sr;
    const float* aptr = (arow < 128) ? (q + arow * DIM) : (p + (arow - 128) * DIM);
    const float* bptr = (brow < 128) ? (q + brow * DIM) : (p + (brow - 128) * DIM);

    float acc[4][4] = {};
    const int kbase = chunk * 192;

    for (int k0 = 0; k0 < 192; k0 += 8) {
        const float4 a4 = *(const float4*)(aptr + kbase + k0 + kq);
        const float4 b4 = *(const float4*)(bptr + kbase + k0 + kq);
        __syncthreads();
        As[kq+0][sr] = a4.x; As[kq+1][sr] = a4.y; As[kq+2][sr] = a4.z; As[kq+3][sr] = a4.w;
        Bs[kq+0][sr] = b4.x; Bs[kq+1][sr] = b4.y; Bs[kq+2][sr] = b4.z; Bs[kq+3][sr] = b4.w;
        __syncthreads();
        #pragma unroll
        for (int k2 = 0; k2 < 8; ++k2) {
            const float4 af = *(const float4*)&As[k2][ty * 4];
            const float4 bf = *(const float4*)&Bs[k2][tx * 4];
            const float ar[4] = {af.x, af.y, af.z, af.w};
            const float br[4] = {bf.x, bf.y, bf.z, bf.w};
            #pragma unroll
            for (int r = 0; r < 4; ++r)
                #pragma unroll
                for (int c = 0; c < 4; ++c)
                    acc[r][c] = fmaf(ar[r], br[c], acc[r][c]);
        }
    }
    #pragma unroll
    for (int r = 0; r < 4; ++r)
        #pragma unroll
        for (int c = 0; c < 4; ++c)
            atomicAdd(&G[(m0 + ty * 4 + r) * N2 + n0 + tx * 4 + c], acc[r][c]);
}

// ---------------------------------------------------------------------------
// prep (blocks 0..255) + contrastive (blocks 256..383), 256 threads.
// prep: inv_s/inv_t, bucketized masked sums of ds/dt.
// contrastive: scores row = 20 * Gs[r, 128+j]; logsumexp - diag -> bucket.
// ---------------------------------------------------------------------------
__global__ __launch_bounds__(256) void prep_kernel(float* __restrict__ ws) {
    const float* Gs = ws + OFF_GS;
    const float* Gt = ws + OFF_GT;
    float* bkt = ws + OFF_BKT;
    const int b = blockIdx.x, t = threadIdx.x;
    __shared__ float red[4], red2[4], sd;

    if (b < 256) {
        const int i = b, j = t;
        const float Gii = Gs[i * 257], Gjj = Gs[j * 257], Gij = Gs[i * N2 + j];
        const float ds = fmaxf(Gii + Gjj - 2.f * Gij, 0.f);
        (ws + OFF_INVS)[i * N2 + j] = 1.f / (sqrtf(ds) + EPSF);
        const float Tii = Gt[i * 257], Tjj = Gt[j * 257], Tij = Gt[i * N2 + j];
        const float dt = fmaxf(Tii + Tjj - 2.f * Tij, 0.f);
        (ws + OFF_INVT)[i * N2 + j] = 1.f / (sqrtf(dt) + EPSF);

        float vs = wave_reduce_sum((j > i) ? ds : 0.f);
        float vt = wave_reduce_sum((j > i) ? dt : 0.f);
        if ((t & 63) == 0) { red[t >> 6] = vs; red2[t >> 6] = vt; }
        __syncthreads();
        if (t == 0) {
            atomicAdd(&bkt[BKT_DS + (b & 63)], red[0] + red[1] + red[2] + red[3]);
            atomicAdd(&bkt[BKT_DT + (b & 63)], red2[0] + red2[1] + red2[2] + red2[3]);
        }
    } else {
        const int r = b - 256, j = t;
        const float s = (j < 128) ? 20.f * Gs[r * N2 + 128 + j] : -INFINITY;
        if (j == r) sd = s;                   // diag score (r < 128 always)
        float m = wave_reduce_max(s);
        if ((t & 63) == 0) red[t >> 6] = m;
        __syncthreads();
        const float mx = fmaxf(fmaxf(red[0], red[1]), fmaxf(red[2], red[3]));
        float e = wave_reduce_sum((j < 128) ? expf(s - mx) : 0.f);
        if ((t & 63) == 0) red2[t >> 6] = e;
        __syncthreads();
        if (t == 0) {
            const float Z = red2[0] + red2[1] + red2[2] + red2[3];
            atomicAdd(&bkt[BKT_CON + (r & 63)], mx + logf(Z) - sd);
        }
    }
}

// ---------------------------------------------------------------------------
// angle (blocks 0..511) + dist (blocks 512..767), 256 threads.
// angle: maskless (diagonal exclusions contribute ~0 exactly/negligibly).
//   block = (i-tile 32, j-tile 16, k-chunk 64); thread = (ii,jj) handles
//   i1=i0+ii and i2=i1+16. J-side via LDS float4, I-side via broadcast global.
// dist: huber(ds/mean_sd - dt/mean_td) over j>i, means from buckets.
// ---------------------------------------------------------------------------
__global__ __launch_bounds__(256) void angle_kernel(float* __restrict__ ws) {
    const float* Gs = ws + OFF_GS;
    const float* Gt = ws + OFF_GT;
    const float* IS = ws + OFF_INVS;
    const float* IT = ws + OFF_INVT;
    float* bkt = ws + OFF_BKT;
    const int b = blockIdx.x, t = threadIdx.x;
    __shared__ float sGJ[16][68], sIJ[16][68], sTJ[16][68], sITJ[16][68];
    __shared__ float red[4];

    if (b < 512) {
        const int k0 = (b & 3) * 64;
        const int j0 = ((b >> 2) & 15) * 16;
        const int i0 = (b >> 6) * 32;
        const int jj = t & 15, ii = t >> 4;
        const int i1 = i0 + ii, i2 = i1 + 16, j = j0 + jj;
        {   // stage J-side rows [16][64] as float4
            const int r = t >> 4, c = (t & 15) * 4;
            const int g = (j0 + r) * N2 + k0 + c;
            *(float4*)&sGJ[r][c]  = *(const float4*)&Gs[g];
            *(float4*)&sIJ[r][c]  = *(const float4*)&IS[g];
            *(float4*)&sTJ[r][c]  = *(const float4*)&Gt[g];
            *(float4*)&sITJ[r][c] = *(const float4*)&IT[g];
        }
        const float Gjj = Gs[j * 257], Tjj = Gt[j * 257];
        const float wis1 = IS[i1 * N2 + j], wit1 = IT[i1 * N2 + j];
        const float wis2 = IS[i2 * N2 + j], wit2 = IT[i2 * N2 + j];
        const float as1 = (Gjj - Gs[i1 * N2 + j]) * wis1;
        const float at1 = (Tjj - Gt[i1 * N2 + j]) * wit1;
        const float as2 = (Gjj - Gs[i2 * N2 + j]) * wis2;
        const float at2 = (Tjj - Gt[i2 * N2 + j]) * wit2;
        const float* gI1 = Gs + i1 * N2 + k0;
        const float* tI1 = Gt + i1 * N2 + k0;
        const float* gI2 = Gs + i2 * N2 + k0;
        const float* tI2 = Gt + i2 * N2 + k0;
        __syncthreads();

        float sum1 = 0.f, sum2 = 0.f;
        for (int c = 0; c < 64; c += 4) {
            const float4 gJ  = *(const float4*)&sGJ[jj][c];
            const float4 iJ  = *(const float4*)&sIJ[jj][c];
            const float4 tJ  = *(const float4*)&sTJ[jj][c];
            const float4 itJ = *(const float4*)&sITJ[jj][c];
            const float4 a1 = *(const float4*)&gI1[c];
            const float4 b1 = *(const float4*)&tI1[c];
            const float4 a2 = *(const float4*)&gI2[c];
            const float4 b2 = *(const float4*)&tI2[c];
            const float gJr[4]  = {gJ.x, gJ.y, gJ.z, gJ.w};
            const float iJr[4]  = {iJ.x, iJ.y, iJ.z, iJ.w};
            const float tJr[4]  = {tJ.x, tJ.y, tJ.z, tJ.w};
            const float itJr[4] = {itJ.x, itJ.y, itJ.z, itJ.w};
            const float a1r[4] = {a1.x, a1.y, a1.z, a1.w};
            const float b1r[4] = {b1.x, b1.y, b1.z, b1.w};
            const float a2r[4] = {a2.x, a2.y, a2.z, a2.w};
            const float b2r[4] = {b2.x, b2.y, b2.z, b2.w};
            #pragma unroll
            for (int e = 0; e < 4; ++e) {
                const float ps1 = fmaf(wis1, a1r[e] - gJr[e], as1) * iJr[e];
                const float pt1 = fmaf(wit1, b1r[e] - tJr[e], at1) * itJr[e];
                const float d1 = ps1 - pt1;
                const float ad1 = fabsf(d1);
                const float m1 = fminf(ad1, 1.f);
                sum1 = fmaf(m1, fmaf(-0.5f, m1, ad1), sum1);

                const float ps2 = fmaf(wis2, a2r[e] - gJr[e], as2) * iJr[e];
                const float pt2 = fmaf(wit2, b2r[e] - tJr[e], at2) * itJr[e];
                const float d2 = ps2 - pt2;
                const float ad2 = fabsf(d2);
                const float m2 = fminf(ad2, 1.f);
                sum2 = fmaf(m2, fmaf(-0.5f, m2, ad2), sum2);
            }
        }
        float v = wave_reduce_sum(sum1 + sum2);
        if ((t & 63) == 0) red[t >> 6] = v;
        __syncthreads();
        if (t == 0)
            atomicAdd(&bkt[BKT_ANG + (b & 63)], red[0] + red[1] + red[2] + red[3]);
    } else {
        // distance loss
        float vds = bkt[BKT_DS + (t & 63)];
        float vdt = bkt[BKT_DT + (t & 63)];
        vds = wave_reduce_sum(vds);
        vdt = wave_reduce_sum(vdt);
        const float rs = 1.f / (__shfl(vds, 0, 64) / 32640.f + EPSF);
        const float rt = 1.f / (__shfl(vdt, 0, 64) / 32640.f + EPSF);

        const int i = b - 512, j = t;
        const float ds = fmaxf(Gs[i * 257] + Gs[j * 257] - 2.f * Gs[i * N2 + j], 0.f);
        const float dt = fmaxf(Gt[i * 257] + Gt[j * 257] - 2.f * Gt[i * N2 + j], 0.f);
        const float d = ds * rs - dt * rt;
        const float a = fabsf(d);
        const float m = fminf(a, 1.f);
        const float h = (j > i) ? m * fmaf(-0.5f, m, a) : 0.f;
        float v = wave_reduce_sum(h);
        if ((t & 63) == 0) red[t >> 6] = v;
        __syncthreads();
        if (t == 0)
            atomicAdd(&bkt[BKT_DIST + (i & 63)], red[0] + red[1] + red[2] + red[3]);
    }
}

// ---------------------------------------------------------------------------
// finalize: wave-reduce buckets, write (total, contrastive, kd)
// ---------------------------------------------------------------------------
__global__ __launch_bounds__(64) void finalize_kernel(const float* __restrict__ bkt,
                                                      float* __restrict__ out) {
    const int t = threadIdx.x;
    float d = wave_reduce_sum(bkt[BKT_DIST + t]);
    float a = wave_reduce_sum(bkt[BKT_ANG + t]);
    float c = wave_reduce_sum(bkt[BKT_CON + t]);
    if (t == 0) {
        const float contrastive = c / 128.f;
        const float dist = d / 32640.f;
        const float ang = a / 16581120.f;   // 256*255*254
        const float kd = 0.5f * dist + 0.5f * ang;
        out[0] = contrastive + kd;
        out[1] = contrastive;
        out[2] = kd;
    }
}

extern "C" void kernel_launch(void* const* d_in, const int* in_sizes, int n_in,
                              void* d_out, int out_size, void* d_ws, size_t ws_size,
                              hipStream_t stream) {
    (void)in_sizes; (void)n_in; (void)out_size; (void)ws_size;
    const float* sq = (const float*)d_in[0];
    const float* sp = (const float*)d_in[1];
    const float* tq = (const float*)d_in[2];
    const float* tp = (const float*)d_in[3];
    float* ws  = (float*)d_ws;
    float* out = (float*)d_out;

    // zero Gs, Gt, buckets (contiguous region)
    hipMemsetAsync(ws, 0, (2 * 65536 + 320) * sizeof(float), stream);

    gemm_kernel<<<512, 64, 0, stream>>>(sq, sp, tq, tp, ws);
    prep_kernel<<<384, 256, 0, stream>>>(ws);
    angle_kernel<<<768, 256, 0, stream>>>(ws);
    finalize_kernel<<<1, 64, 0, stream>>>(ws + OFF_BKT, out);
}